// Round 6
// baseline (19.082 us; speedup 1.0000x reference)
//
#include <hip/hip_runtime.h>
#include <math.h>

#define NCLUST 16
#define MBLK 512
#define THR 256
#define SPAN (MBLK * THR)   // 131072 float4s per chunk

typedef float f32x2 __attribute__((ext_vector_type(2)));

// Pass 1: stream X with a fully-unrolled 4-deep batch (all loads issued before
// compute), packed-fp32 math, per-block double partial. No fences/atomics.
__global__ __launch_bounds__(THR) void gmm_main_kernel(
    const float* __restrict__ X,
    const float* __restrict__ means,
    const float* __restrict__ chols,
    const float* __restrict__ weights,
    double* __restrict__ partials,
    int nvec)
{
    __shared__ float par[NCLUST][8];
    const int tid = threadIdx.x;
    if (tid < NCLUST) {
        const int k = tid;
        // chols layout [K,2,2] row-major; tril -> L00, L10, L11
        const float c00 = chols[4*k + 0];
        const float c10 = chols[4*k + 2];
        const float c11 = chols[4*k + 3];
        const float s11 = c00*c00;                 // S = L L^T
        const float s12 = c00*c10;
        const float s22 = c10*c10 + c11*c11;
        const float det = s11*s22 - s12*s12;
        const float invdet = 1.0f / det;
        const float KC = -0.7213475204444817f;     // -0.5 * log2(e)
        const float A = KC * s22 * invdet;
        const float B = KC * (-2.0f * s12) * invdet;
        const float C = KC * s11 * invdet;
        const float mx = means[2*k + 0];
        const float my = means[2*k + 1];
        const float coef = weights[k] / (6.283185307179586f * sqrtf(det));
        // t(x,y) = A x^2 + B xy + C y^2 + D x + E y + F ; exp(-m/2)*|coef| = 2^t
        const float D = -(2.0f*A*mx + B*my);
        const float E = -(2.0f*C*my + B*mx);
        const float F = A*mx*mx + B*mx*my + C*my*my + log2f(fabsf(coef));
        par[k][0] = A;  par[k][1] = B;  par[k][2] = C;
        par[k][3] = D;  par[k][4] = E;  par[k][5] = F;
        par[k][6] = (coef < 0.0f) ? -1.0f : 1.0f;
    }
    __syncthreads();

    float a[NCLUST], b[NCLUST], c[NCLUST], d[NCLUST], e[NCLUST], f[NCLUST], sg[NCLUST];
    #pragma unroll
    for (int k = 0; k < NCLUST; ++k) {
        a[k] = par[k][0]; b[k] = par[k][1]; c[k] = par[k][2];
        d[k] = par[k][3]; e[k] = par[k][4]; f[k] = par[k][5];
        sg[k] = par[k][6];
    }

    const float4* __restrict__ X4 = (const float4*)X;
    f32x2 acc2 = {0.0f, 0.0f};
    const int idx = blockIdx.x * THR + tid;

    // grid-stride outer loop (executes once for nvec <= 4*SPAN = 524288)
    for (int bse = idx; bse < nvec; bse += 4 * SPAN) {
        const int i1 = bse + SPAN, i2 = bse + 2*SPAN, i3 = bse + 3*SPAN;
        const bool ok1 = i1 < nvec, ok2 = i2 < nvec, ok3 = i3 < nvec;
        // issue all four 16B loads before any compute (latency overlap)
        const float4 v0 = X4[bse];
        const float4 v1 = X4[ok1 ? i1 : 0];
        const float4 v2 = X4[ok2 ? i2 : 0];
        const float4 v3 = X4[ok3 ? i3 : 0];

        const f32x2 px[4] = {{v0.x,v0.z},{v1.x,v1.z},{v2.x,v2.z},{v3.x,v3.z}};
        const f32x2 py[4] = {{v0.y,v0.w},{v1.y,v1.w},{v2.y,v2.w},{v3.y,v3.w}};
        f32x2 g[4] = {{0,0},{0,0},{0,0},{0,0}};
        #pragma unroll
        for (int k = 0; k < NCLUST; ++k) {
            #pragma unroll
            for (int j = 0; j < 4; ++j) {
                // t = px*(A*px + B*py + D) + (py*(C*py + E) + F)  [5 pk-fma]
                const f32x2 u  = a[k]*px[j] + (b[k]*py[j] + d[k]);
                const f32x2 w2 = c[k]*py[j] + e[k];
                const f32x2 t  = u*px[j] + (w2*py[j] + f[k]);
                const f32x2 ev = { __builtin_amdgcn_exp2f(t.x),
                                   __builtin_amdgcn_exp2f(t.y) };
                g[j] = sg[k]*ev + g[j];
            }
        }
        // accumulate in chunk order 0,1,2,3 (bit-identical to r5's loop order)
        acc2 = g[0]*g[0] + acc2;
        const f32x2 m1 = {ok1 ? 1.0f : 0.0f, ok1 ? 1.0f : 0.0f};
        const f32x2 m2 = {ok2 ? 1.0f : 0.0f, ok2 ? 1.0f : 0.0f};
        const f32x2 m3 = {ok3 ? 1.0f : 0.0f, ok3 ? 1.0f : 0.0f};
        acc2 = (g[1]*g[1])*m1 + acc2;
        acc2 = (g[2]*g[2])*m2 + acc2;
        acc2 = (g[3]*g[3])*m3 + acc2;
    }
    float acc = acc2.x + acc2.y;

    // wave (64-lane) reduction, then cross-wave via LDS
    #pragma unroll
    for (int off = 32; off > 0; off >>= 1)
        acc += __shfl_down(acc, off, 64);
    __shared__ float wsum[THR / 64];
    if ((tid & 63) == 0) wsum[tid >> 6] = acc;
    __syncthreads();
    if (tid == 0) {
        float s = 0.0f;
        #pragma unroll
        for (int w = 0; w < THR / 64; ++w) s += wsum[w];
        partials[blockIdx.x] = (double)s;
    }
}

// Pass 2: single-wave finalize. 8 partials + 4 z-pairs per lane, shfl-only
// reductions (no LDS trees, no multi-wave barriers).
__global__ __launch_bounds__(64) void gmm_final_kernel(
    const float* __restrict__ X,
    const float* __restrict__ means,
    const float* __restrict__ chols,
    const float* __restrict__ weights,
    const double* __restrict__ partials,
    float* __restrict__ out,
    int nblocks,
    int nsamples)
{
    const int tid = threadIdx.x;
    __shared__ float s11s[NCLUST], s12s[NCLUST], s22s[NCLUST];
    __shared__ float wv[NCLUST], mxs[NCLUST], mys[NCLUST];
    if (tid < NCLUST) {
        const float c00 = chols[4*tid + 0];
        const float c10 = chols[4*tid + 2];
        const float c11 = chols[4*tid + 3];
        s11s[tid] = c00*c00;
        s12s[tid] = c00*c10;
        s22s[tid] = c10*c10 + c11*c11;
        wv[tid]  = weights[tid];
        mxs[tid] = means[2*tid + 0];
        mys[tid] = means[2*tid + 1];
    }
    __syncthreads();

    // 4 cluster pairs per lane (256 pairs total), fixed order
    double zsum = 0.0;
    #pragma unroll
    for (int p4 = 0; p4 < 4; ++p4) {
        const int p = tid * 4 + p4;
        const int i = p >> 4, j = p & 15;
        const float t11 = s11s[i] + s11s[j];
        const float t12 = s12s[i] + s12s[j];
        const float t22 = s22s[i] + s22s[j];
        const float det = t11*t22 - t12*t12;
        const float mdx = mxs[i] - mxs[j];
        const float mdy = mys[i] - mys[j];
        const float m2 = (t22*mdx*mdx - 2.0f*t12*mdx*mdy + t11*mdy*mdy) / det;
        const float Zij = expf(-0.5f * m2) / (6.283185307179586f * sqrtf(det));
        zsum += (double)(wv[i] * wv[j] * Zij);
    }

    // per-lane partial sums (8 each), fixed order
    double ps = 0.0;
    for (int bi = tid; bi < nblocks; bi += 64) ps += partials[bi];

    // odd-sample tail (never hit for N=2M; recompute coefs locally if needed)
    if (tid == 0 && (nsamples & 1)) {
        const float x = X[2*(nsamples-1)], y = X[2*(nsamples-1)+1];
        float gg = 0.0f;
        for (int k = 0; k < NCLUST; ++k) {
            const float s11 = s11s[k], s12 = s12s[k], s22 = s22s[k];
            const float det = s11*s22 - s12*s12;
            const float dx = x - mxs[k], dy = y - mys[k];
            const float m = (s22*dx*dx - 2.0f*s12*dx*dy + s11*dy*dy) / det;
            gg += wv[k] * expf(-0.5f*m) / (6.283185307179586f * sqrtf(det));
        }
        ps += (double)(gg*gg);
    }

    // single-wave shfl reduction of both doubles
    #pragma unroll
    for (int off = 32; off > 0; off >>= 1) {
        ps   += __shfl_down(ps,   off, 64);
        zsum += __shfl_down(zsum, off, 64);
    }
    if (tid == 0)
        out[0] = (float)(-(log(ps) - log(zsum)) / (double)nsamples);
}

extern "C" void kernel_launch(void* const* d_in, const int* in_sizes, int n_in,
                              void* d_out, int out_size, void* d_ws, size_t ws_size,
                              hipStream_t stream)
{
    const float* X       = (const float*)d_in[0];
    const float* means   = (const float*)d_in[1];
    const float* chols   = (const float*)d_in[2];
    const float* weights = (const float*)d_in[3];
    float* out = (float*)d_out;
    double* partials = (double*)d_ws;   // MBLK doubles

    const int nsamples = in_sizes[0] / 2;   // X is [N,2]
    const int nvec = nsamples / 2;          // float4 = 2 samples

    gmm_main_kernel<<<MBLK, THR, 0, stream>>>(
        X, means, chols, weights, partials, nvec);
    gmm_final_kernel<<<1, 64, 0, stream>>>(
        X, means, chols, weights, partials, out, MBLK, nsamples);
}

// Round 7
// 16.448 us; speedup vs baseline: 1.1601x; 1.1601x over previous
//
#include <hip/hip_runtime.h>
#include <math.h>

#define NCLUST 16
#define MAIN_BLOCKS 512
#define THREADS 256

typedef float f32x2 __attribute__((ext_vector_type(2)));

// Pass 1: stream X, packed-fp32 math (v_pk_fma_f32 pairing of the two samples
// in each float4), per-block double partial. No fences, no atomics.
// NOTE (r6 post-mortem): 4-deep manual unroll REGRESSED (16.26->19.08 us) --
// VGPR growth + masked-lane waste + scattered addresses. Keep the compact
// grid-stride loop; the compiler's schedule is already latency-clean here.
__global__ __launch_bounds__(THREADS) void gmm_main_kernel(
    const float* __restrict__ X,
    const float* __restrict__ means,
    const float* __restrict__ chols,
    const float* __restrict__ weights,
    double* __restrict__ partials,
    int nvec)
{
    __shared__ float par[NCLUST][8];
    const int tid = threadIdx.x;
    if (tid < NCLUST) {
        const int k = tid;
        // chols layout [K,2,2] row-major; tril -> L00, L10, L11
        const float c00 = chols[4*k + 0];
        const float c10 = chols[4*k + 2];
        const float c11 = chols[4*k + 3];
        const float s11 = c00*c00;                 // S = L L^T
        const float s12 = c00*c10;
        const float s22 = c10*c10 + c11*c11;
        const float det = s11*s22 - s12*s12;
        const float invdet = 1.0f / det;
        const float KC = -0.7213475204444817f;     // -0.5 * log2(e)
        const float A = KC * s22 * invdet;
        const float B = KC * (-2.0f * s12) * invdet;
        const float C = KC * s11 * invdet;
        const float mx = means[2*k + 0];
        const float my = means[2*k + 1];
        const float coef = weights[k] / (6.283185307179586f * sqrtf(det));
        // t(x,y) = A x^2 + B xy + C y^2 + D x + E y + F ; exp(-m/2)*|coef| = 2^t
        const float D = -(2.0f*A*mx + B*my);
        const float E = -(2.0f*C*my + B*mx);
        const float F = A*mx*mx + B*mx*my + C*my*my + log2f(fabsf(coef));
        par[k][0] = A;  par[k][1] = B;  par[k][2] = C;
        par[k][3] = D;  par[k][4] = E;  par[k][5] = F;
        par[k][6] = (coef < 0.0f) ? -1.0f : 1.0f;
    }
    __syncthreads();

    float a[NCLUST], b[NCLUST], c[NCLUST], d[NCLUST], e[NCLUST], f[NCLUST], sg[NCLUST];
    #pragma unroll
    for (int k = 0; k < NCLUST; ++k) {
        a[k] = par[k][0]; b[k] = par[k][1]; c[k] = par[k][2];
        d[k] = par[k][3]; e[k] = par[k][4]; f[k] = par[k][5];
        sg[k] = par[k][6];
    }

    const float4* __restrict__ X4 = (const float4*)X;
    f32x2 acc2 = {0.0f, 0.0f};
    const int stride = MAIN_BLOCKS * THREADS;
    for (int i = blockIdx.x * THREADS + tid; i < nvec; i += stride) {
        const float4 v = X4[i];            // two samples: (v.x,v.y), (v.z,v.w)
        const f32x2 px = {v.x, v.z};
        const f32x2 py = {v.y, v.w};
        f32x2 g = {0.0f, 0.0f};
        #pragma unroll
        for (int k = 0; k < NCLUST; ++k) {
            // t = px*(A*px + B*py + D) + (py*(C*py + E) + F)   [5 pk-fma]
            const f32x2 u  = a[k]*px + (b[k]*py + d[k]);
            const f32x2 w2 = c[k]*py + e[k];
            const f32x2 t  = u*px + (w2*py + f[k]);
            const f32x2 ev = { __builtin_amdgcn_exp2f(t.x),
                               __builtin_amdgcn_exp2f(t.y) };
            g = sg[k]*ev + g;              // 1 pk-fma
        }
        acc2 = g*g + acc2;                 // 1 pk-fma
    }
    float acc = acc2.x + acc2.y;

    // wave (64-lane) reduction, then cross-wave via LDS
    #pragma unroll
    for (int off = 32; off > 0; off >>= 1)
        acc += __shfl_down(acc, off, 64);
    __shared__ float wsum[THREADS / 64];
    if ((tid & 63) == 0) wsum[tid >> 6] = acc;
    __syncthreads();
    if (tid == 0) {
        float s = 0.0f;
        #pragma unroll
        for (int w = 0; w < THREADS / 64; ++w) s += wsum[w];
        partials[blockIdx.x] = (double)s;
    }
}

// Pass 2: 16x16 pair normalizer z, reduce block partials, final scalar.
__global__ __launch_bounds__(THREADS) void gmm_final_kernel(
    const float* __restrict__ means,
    const float* __restrict__ chols,
    const float* __restrict__ weights,
    const double* __restrict__ partials,
    float* __restrict__ out,
    int nblocks,
    int nsamples)
{
    const int tid = threadIdx.x;
    __shared__ float s11s[NCLUST], s12s[NCLUST], s22s[NCLUST];
    __shared__ float wv[NCLUST], mxs[NCLUST], mys[NCLUST];
    if (tid < NCLUST) {
        const float c00 = chols[4*tid + 0];
        const float c10 = chols[4*tid + 2];
        const float c11 = chols[4*tid + 3];
        s11s[tid] = c00*c00;
        s12s[tid] = c00*c10;
        s22s[tid] = c10*c10 + c11*c11;
        wv[tid]  = weights[tid];
        mxs[tid] = means[2*tid + 0];
        mys[tid] = means[2*tid + 1];
    }
    __syncthreads();

    // one (i,j) cluster pair per thread (256 = 16*16)
    const int i = tid >> 4, j = tid & 15;
    const float t11 = s11s[i] + s11s[j];
    const float t12 = s12s[i] + s12s[j];
    const float t22 = s22s[i] + s22s[j];
    const float det = t11*t22 - t12*t12;
    const float mdx = mxs[i] - mxs[j];
    const float mdy = mys[i] - mys[j];
    const float m2 = (t22*mdx*mdx - 2.0f*t12*mdx*mdy + t11*mdy*mdy) / det;
    const float Zij = expf(-0.5f * m2) / (6.283185307179586f * sqrtf(det));
    double zc = (double)(wv[i] * wv[j] * Zij);

    // sum the per-block g^2 partials (fixed order)
    double ps = 0.0;
    for (int bi = tid; bi < nblocks; bi += THREADS) ps += partials[bi];

    __shared__ double red[THREADS], red2[THREADS];
    red[tid] = ps;
    red2[tid] = zc;
    __syncthreads();
    for (int s = 128; s > 0; s >>= 1) {
        if (tid < s) { red[tid] += red[tid + s]; red2[tid] += red2[tid + s]; }
        __syncthreads();
    }
    if (tid == 0) {
        const double total = red[0];   // sum_n g(x_n)^2
        const double z = red2[0];      // pair normalizer
        out[0] = (float)(-(log(total) - log(z)) / (double)nsamples);
    }
}

extern "C" void kernel_launch(void* const* d_in, const int* in_sizes, int n_in,
                              void* d_out, int out_size, void* d_ws, size_t ws_size,
                              hipStream_t stream)
{
    const float* X       = (const float*)d_in[0];
    const float* means   = (const float*)d_in[1];
    const float* chols   = (const float*)d_in[2];
    const float* weights = (const float*)d_in[3];
    float* out = (float*)d_out;
    double* partials = (double*)d_ws;   // MAIN_BLOCKS doubles

    const int nsamples = in_sizes[0] / 2;   // X is [N,2]
    const int nvec = nsamples / 2;          // float4 = 2 samples

    gmm_main_kernel<<<MAIN_BLOCKS, THREADS, 0, stream>>>(
        X, means, chols, weights, partials, nvec);
    gmm_final_kernel<<<1, THREADS, 0, stream>>>(
        means, chols, weights, partials, out, MAIN_BLOCKS, nsamples);
}